// Round 7
// baseline (84.560 us; speedup 1.0000x reference)
//
#include <hip/hip_runtime.h>
#include <math.h>

#define NNODE 32768   // B*N
constexpr float SCALE = 0.08838834764831845f; // 1/sqrt(128)

typedef unsigned short u16;
typedef __bf16 bf16x8 __attribute__((ext_vector_type(8)));
typedef float f32x4 __attribute__((ext_vector_type(4)));

__device__ __forceinline__ u16 f2bf(float f) {
    unsigned u = __float_as_uint(f);
    u += 0x7fff + ((u >> 16) & 1);       // RNE
    return (u16)(u >> 16);
}
__device__ __forceinline__ unsigned pack2bf(float lo, float hi) {
    return (unsigned)f2bf(lo) | ((unsigned)f2bf(hi) << 16);
}
__device__ __forceinline__ void unpack8(uint4 u, float* f) {
    f[0] = __uint_as_float(u.x << 16);  f[1] = __uint_as_float(u.x & 0xffff0000u);
    f[2] = __uint_as_float(u.y << 16);  f[3] = __uint_as_float(u.y & 0xffff0000u);
    f[4] = __uint_as_float(u.z << 16);  f[5] = __uint_as_float(u.z & 0xffff0000u);
    f[6] = __uint_as_float(u.w << 16);  f[7] = __uint_as_float(u.w & 0xffff0000u);
}
__device__ __forceinline__ float dot128(const float* __restrict__ a,
                                        const float* __restrict__ b) {
    float s = 0.f;
    #pragma unroll
    for (int c = 0; c < 128; c += 4) {
        float4 x = *(const float4*)&a[c];
        float4 y = *(const float4*)&b[c];
        s = fmaf(x.x, y.x, s); s = fmaf(x.y, y.y, s);
        s = fmaf(x.z, y.z, s); s = fmaf(x.w, y.w, s);
    }
    return s;
}

// async global->LDS, 16B per lane; LDS dest must be wave-uniform base
__device__ __forceinline__ void gl_lds16(const void* g, void* l) {
    __builtin_amdgcn_global_load_lds(
        (const __attribute__((address_space(1))) unsigned int*)(uintptr_t)g,
        (__attribute__((address_space(3))) unsigned int*)(unsigned int)(uintptr_t)l,
        16, 0, 0);
}

// ---------------- prep: xconv (blocks 0..2047) + wprep1 (2048..2559) ----
// xconv: Xb = bf16(X)
// wprep1: Af=Wq@wq^T, Bmf=Wk@wk^T, Wtf=Wv@wv^T, RT[g][f]=sum_e ow[e][f]*lin_w[g][dir*128+e]
__global__ __launch_bounds__(256) void prep(
    const float* __restrict__ X, u16* __restrict__ Xb,
    const float* __restrict__ ipw_in, const float* __restrict__ ipw_out,
    const float* __restrict__ Wq_in, const float* __restrict__ Wk_in,
    const float* __restrict__ Wv_in,
    const float* __restrict__ Wq_out, const float* __restrict__ Wk_out,
    const float* __restrict__ Wv_out,
    const float* __restrict__ ow_in, const float* __restrict__ ow_out,
    const float* __restrict__ lin_w,
    float* __restrict__ Af, float* __restrict__ Bmf,
    float* __restrict__ Wtf, float* __restrict__ RTf)
{
    if (blockIdx.x < 2048) {
        int t = blockIdx.x * 256 + threadIdx.x;   // one thread = 8 elems
        float4 a = *(const float4*)&X[(size_t)t * 8];
        float4 b = *(const float4*)&X[(size_t)t * 8 + 4];
        uint4 pk;
        pk.x = pack2bf(a.x, a.y); pk.y = pack2bf(a.z, a.w);
        pk.z = pack2bf(b.x, b.y); pk.w = pack2bf(b.z, b.w);
        *(uint4*)&Xb[(size_t)t * 8] = pk;
        return;
    }
    int flat = blockIdx.x - 2048;                 // 0..511
    int task = flat >> 6, blk = flat & 63;
    int t = blk * 256 + threadIdx.x;              // 0..16383
    int i = t >> 7, j = t & 127;
    int dir = task & 1, kind = task >> 1;
    if (kind < 3) {
        const float* ipw = dir ? ipw_out : ipw_in;
        const float* W; const float* w; float* outp;
        if (kind == 0)      { W = dir ? Wq_out : Wq_in; w = ipw;          outp = Af;  }
        else if (kind == 1) { W = dir ? Wk_out : Wk_in; w = ipw + 16384;  outp = Bmf; }
        else                { W = dir ? Wv_out : Wv_in; w = ipw + 32768;  outp = Wtf; }
        outp[dir * 16384 + i * 128 + j] = dot128(W + i * 128, w + j * 128);
    } else {
        const float* ow = dir ? ow_out : ow_in;
        const float* lw = lin_w + i * 256 + dir * 128;
        float s = 0.f;
        #pragma unroll
        for (int e = 0; e < 128; e += 4) {
            float4 l4 = *(const float4*)&lw[e];
            s = fmaf(ow[e * 128 + j],       l4.x, s);
            s = fmaf(ow[(e + 1) * 128 + j], l4.y, s);
            s = fmaf(ow[(e + 2) * 128 + j], l4.z, s);
            s = fmaf(ow[(e + 3) * 128 + j], l4.w, s);
        }
        RTf[dir * 16384 + i * 128 + j] = s;
    }
}

// ---------------- weight prep stage 2 ----------------------------------
// Bcat[dir*128+d][c] = sum_f A[c][f]*Bm[d][f]   (bf16)
// QfT[g][dir*128+c]  = sum_f Wt[c][f]*RT[g][f]  (bf16)
// ycat[dir*128+d] = Bm_row_d . bq ; bfin[g] = lin_b[g] + sum_dir(bv.RT_g + ob.lw_g)
__global__ __launch_bounds__(256) void wprep2(
    const float* __restrict__ Af, const float* __restrict__ Bmf,
    const float* __restrict__ Wtf, const float* __restrict__ RTf,
    const float* __restrict__ ipb_in, const float* __restrict__ ipb_out,
    const float* __restrict__ lin_w, const float* __restrict__ lin_b,
    const float* __restrict__ ob_in, const float* __restrict__ ob_out,
    u16* __restrict__ Bcat, u16* __restrict__ QfT,
    float* __restrict__ ycat, float* __restrict__ bfin)
{
    int task = blockIdx.y;
    int t = blockIdx.x * 256 + threadIdx.x;
    if (task < 2) {
        int dir = task, i = t >> 7, j = t & 127;          // i=d, j=c
        float s = dot128(Af + dir * 16384 + j * 128, Bmf + dir * 16384 + i * 128);
        Bcat[(size_t)(dir * 128 + i) * 128 + j] = f2bf(s);
    } else if (task < 4) {
        int dir = task - 2, i = t >> 7, j = t & 127;      // i=g, j=c
        float s = dot128(Wtf + dir * 16384 + j * 128, RTf + dir * 16384 + i * 128);
        QfT[(size_t)i * 256 + dir * 128 + j] = f2bf(s);
    } else {
        if (t < 256) {
            int dir = t >> 7, d = t & 127;
            const float* bq = dir ? ipb_out : ipb_in;
            const float* rb = Bmf + dir * 16384 + d * 128;
            float s = 0.f;
            for (int f = 0; f < 128; ++f) s = fmaf(rb[f], bq[f], s);
            ycat[t] = s;
        } else if (t < 384) {
            int g = t - 256;
            float s = lin_b[g];
            #pragma unroll
            for (int dir = 0; dir < 2; ++dir) {
                const float* bv = (dir ? ipb_out : ipb_in) + 256;
                const float* rt = RTf + dir * 16384 + g * 128;
                const float* ob = dir ? ob_out : ob_in;
                const float* lw = lin_w + g * 256 + dir * 128;
                for (int c = 0; c < 128; ++c)
                    s += bv[c] * rt[c] + ob[c] * lw[c];
            }
            bfin[g] = s;
        }
    }
}

// ---------------- megakernel: Y-GEMM + attn + out-GEMM per 32 nodes -----
// P1: Y[32][256] = XbTile @ Bcat^T + ycat (LDS, never global)
// P2: attn (64 items, 4 rounds of 16 groups), XCTX -> LDS
// P3: out[32][128] = elu(XCTX @ QfT^T + bfin) -> d_out (f32)
// bid swizzle: batch b blocks occupy bid%8 in {2b,2b+1} -> per-XCD 2MB Xb pool
__global__ __launch_bounds__(256) void mega(
    const u16* __restrict__ Xb, const u16* __restrict__ Bcat,
    const float* __restrict__ ycat, const u16* __restrict__ QfT,
    const float* __restrict__ bfin,
    const int* __restrict__ in_idx, const int* __restrict__ out_idx,
    const int* __restrict__ in_mask, const int* __restrict__ out_mask,
    float* __restrict__ Cout)
{
    __shared__ __align__(16) u16 XbT[32 * 128];   //  8 KB, A tile (swz)
    __shared__ __align__(16) u16 Yl[32 * 256];    // 16 KB (swz)
    __shared__ __align__(16) u16 XC[32 * 256];    // 16 KB (swz)

    const int tid  = threadIdx.x;
    const int lane = tid & 63;
    const int wid  = tid >> 6;
    const int l15  = lane & 15, l4 = lane >> 4;

    const int bid  = blockIdx.x;
    const int b    = (bid & 7) >> 1;
    const int s    = ((bid >> 3) << 1) + (bid & 1);   // 0..255
    const int node0 = (b << 13) + s * 32;

    // ---- P0: stage Xb tile [32][128] (swizzled via pre-swizzled source) ----
    #pragma unroll
    for (int i = 0; i < 2; ++i) {
        int c = i * 256 + tid;           // chunk 0..511
        int r = c >> 4, cb = c & 15;
        gl_lds16(&Xb[(size_t)(node0 + r) * 128 + 8 * (cb ^ (r & 7))],
                 &XbT[(size_t)(c - lane) * 8]);
    }
    __syncthreads();

    // ---- P1: Y = XbT @ Bcat^T + ycat ; wave w: cols w*64.., mr 0..1, nc 0..3
    {
        f32x4 acc[2][4] = {};
        #pragma unroll
        for (int ks = 0; ks < 4; ++ks) {
            bf16x8 a[2], bb[4];
            #pragma unroll
            for (int mr = 0; mr < 2; ++mr) {
                int r = mr * 16 + l15;
                int kb = ks * 4 + l4;
                a[mr] = *(const bf16x8*)((const char*)XbT + r * 256 + ((kb ^ (r & 7)) << 4));
            }
            #pragma unroll
            for (int nc = 0; nc < 4; ++nc) {
                int col = wid * 64 + nc * 16 + l15;
                bb[nc] = *(const bf16x8*)&Bcat[(size_t)col * 128 + (ks * 4 + l4) * 8];
            }
            #pragma unroll
            for (int mr = 0; mr < 2; ++mr)
                #pragma unroll
                for (int nc = 0; nc < 4; ++nc)
                    acc[mr][nc] = __builtin_amdgcn_mfma_f32_16x16x32_bf16(
                        a[mr], bb[nc], acc[mr][nc], 0, 0, 0);
        }
        float yb[4];
        #pragma unroll
        for (int nc = 0; nc < 4; ++nc) yb[nc] = ycat[wid * 64 + nc * 16 + l15];
        #pragma unroll
        for (int mr = 0; mr < 2; ++mr)
            #pragma unroll
            for (int nc = 0; nc < 4; ++nc) {
                int col = wid * 64 + nc * 16 + l15;
                int chunk = col >> 3, within = col & 7;
                #pragma unroll
                for (int j = 0; j < 4; ++j) {
                    int row = mr * 16 + l4 * 4 + j;
                    *(u16*)((char*)Yl + row * 512 + ((chunk ^ (row & 7)) << 4) + within * 2)
                        = f2bf(acc[mr][nc][j] + yb[nc]);
                }
            }
    }
    __syncthreads();

    // ---- P2: attention, 64 items (node r, dir), 4 rounds of 16 groups ----
    {
        const int g = tid >> 4, l = tid & 15;
        #pragma unroll
        for (int round = 0; round < 4; ++round) {
            int item = round * 16 + g;
            int r   = item & 31;
            int dir = item >> 5;
            int node = node0 + r;
            const int* idx = dir ? out_idx : in_idx;
            const int* msk = dir ? out_mask : in_mask;

            const int4 i0 = *(const int4*)&idx[(size_t)node * 8];
            const int4 i1 = *(const int4*)&idx[(size_t)node * 8 + 4];
            const int4 m0 = *(const int4*)&msk[(size_t)node * 8];
            const int4 m1 = *(const int4*)&msk[(size_t)node * 8 + 4];
            const int ii[8] = { i0.x, i0.y, i0.z, i0.w, i1.x, i1.y, i1.z, i1.w };
            const int mm[8] = { m0.x, m0.y, m0.z, m0.w, m1.x, m1.y, m1.z, m1.w };

            // Y row (self) from LDS; self Xb from LDS; 8 gathered rows global
            uint4 yv = *(const uint4*)((const char*)Yl + r * 512 +
                           ((((dir << 4) + l) ^ (r & 7)) << 4));
            uint4 xv[9];
            xv[0] = *(const uint4*)((const char*)XbT + r * 256 + ((l ^ (r & 7)) << 4));
            #pragma unroll
            for (int t2 = 0; t2 < 8; ++t2)
                xv[t2 + 1] = *(const uint4*)&Xb[(size_t)((b << 13) + ii[t2]) * 128 + l * 8];

            float yf[8];
            unpack8(yv, yf);
            float sc[9];
            #pragma unroll
            for (int t2 = 0; t2 < 9; ++t2) {
                float kf[8];
                unpack8(xv[t2], kf);
                float d = 0.f;
                #pragma unroll
                for (int j = 0; j < 8; ++j) d = fmaf(yf[j], kf[j], d);
                sc[t2] = d;
            }
            #pragma unroll
            for (int t2 = 0; t2 < 9; ++t2) {
                float x = sc[t2];
                x += __shfl_xor(x, 1);
                x += __shfl_xor(x, 2);
                x += __shfl_xor(x, 4);
                x += __shfl_xor(x, 8);
                sc[t2] = x * SCALE;
            }
            #pragma unroll
            for (int t2 = 1; t2 < 9; ++t2)
                sc[t2] = mm[t2 - 1] ? sc[t2] : -1e30f;

            float m = sc[0];
            #pragma unroll
            for (int t2 = 1; t2 < 9; ++t2) m = fmaxf(m, sc[t2]);
            float w[9], wsum = 0.f;
            #pragma unroll
            for (int t2 = 0; t2 < 9; ++t2) { w[t2] = __expf(sc[t2] - m); wsum += w[t2]; }
            const float inv = 1.f / wsum;

            float acc[8] = {};
            #pragma unroll
            for (int t2 = 0; t2 < 9; ++t2) {
                float vf[8];
                unpack8(xv[t2], vf);
                #pragma unroll
                for (int j = 0; j < 8; ++j) acc[j] = fmaf(w[t2], vf[j], acc[j]);
            }
            uint4 o;
            o.x = pack2bf(acc[0] * inv, acc[1] * inv);
            o.y = pack2bf(acc[2] * inv, acc[3] * inv);
            o.z = pack2bf(acc[4] * inv, acc[5] * inv);
            o.w = pack2bf(acc[6] * inv, acc[7] * inv);
            *(uint4*)((char*)XC + r * 512 + ((((dir << 4) + l) ^ (r & 7)) << 4)) = o;
        }
    }
    __syncthreads();

    // ---- P3: out = elu(XC @ QfT^T + bfin) ; wave w: cols w*32.., mr 0..1, nc 0..1
    {
        f32x4 acc[2][2] = {};
        #pragma unroll
        for (int ks = 0; ks < 8; ++ks) {
            bf16x8 a[2], bb[2];
            #pragma unroll
            for (int mr = 0; mr < 2; ++mr) {
                int r = mr * 16 + l15;
                int kb = ks * 4 + l4;
                a[mr] = *(const bf16x8*)((const char*)XC + r * 512 + ((kb ^ (r & 7)) << 4));
            }
            #pragma unroll
            for (int nc = 0; nc < 2; ++nc) {
                int col = wid * 32 + nc * 16 + l15;
                bb[nc] = *(const bf16x8*)&QfT[(size_t)col * 256 + (ks * 4 + l4) * 8];
            }
            #pragma unroll
            for (int mr = 0; mr < 2; ++mr)
                #pragma unroll
                for (int nc = 0; nc < 2; ++nc)
                    acc[mr][nc] = __builtin_amdgcn_mfma_f32_16x16x32_bf16(
                        a[mr], bb[nc], acc[mr][nc], 0, 0, 0);
        }
        #pragma unroll
        for (int nc = 0; nc < 2; ++nc) {
            int col = wid * 32 + nc * 16 + l15;
            float bv = bfin[col];
            #pragma unroll
            for (int mr = 0; mr < 2; ++mr)
                #pragma unroll
                for (int j = 0; j < 4; ++j) {
                    int row = mr * 16 + l4 * 4 + j;
                    float v = acc[mr][nc][j] + bv;
                    v = v > 0.f ? v : (__expf(v) - 1.f);
                    Cout[(size_t)(node0 + row) * 128 + col] = v;
                }
        }
    }
}

// ---------------- launch ----------------------------------------------
extern "C" void kernel_launch(void* const* d_in, const int* in_sizes, int n_in,
                              void* d_out, int out_size, void* d_ws, size_t ws_size,
                              hipStream_t stream) {
    const float* X        = (const float*)d_in[0];
    const int*   in_idx   = (const int*)d_in[1];
    const int*   out_idx  = (const int*)d_in[2];
    const int*   in_mask  = (const int*)d_in[3];
    const int*   out_mask = (const int*)d_in[4];
    const float* Wq_in  = (const float*)d_in[5];
    const float* Wk_in  = (const float*)d_in[6];
    const float* Wv_in  = (const float*)d_in[7];
    const float* ipw_in = (const float*)d_in[8];
    const float* ipb_in = (const float*)d_in[9];
    const float* ow_in  = (const float*)d_in[10];
    const float* ob_in  = (const float*)d_in[11];
    const float* Wq_out  = (const float*)d_in[12];
    const float* Wk_out  = (const float*)d_in[13];
    const float* Wv_out  = (const float*)d_in[14];
    const float* ipw_out = (const float*)d_in[15];
    const float* ipb_out = (const float*)d_in[16];
    const float* ow_out  = (const float*)d_in[17];
    const float* ob_out  = (const float*)d_in[18];
    const float* lin_w   = (const float*)d_in[19];
    const float* lin_b   = (const float*)d_in[20];

    char* wsb = (char*)d_ws;
    u16*   Xbw  = (u16*)(wsb + 0);                    //  8,388,608 B
    u16*   Bcat = (u16*)(wsb + 8388608);              //     65,536 B
    u16*   QfT  = (u16*)(wsb + 8454144);              //     65,536 B
    float* Af   = (float*)(wsb + 8519680);            //    131,072 B
    float* Bmf  = (float*)(wsb + 8650752);
    float* Wtf  = (float*)(wsb + 8781824);
    float* RTf  = (float*)(wsb + 8912896);
    float* ycat = (float*)(wsb + 9043968);            //      1,024 B
    float* bfin = (float*)(wsb + 9044992);            //        512 B

    prep<<<2560, 256, 0, stream>>>(
        X, Xbw, ipw_in, ipw_out, Wq_in, Wk_in, Wv_in, Wq_out, Wk_out, Wv_out,
        ow_in, ow_out, lin_w, Af, Bmf, Wtf, RTf);

    wprep2<<<dim3(64, 5), 256, 0, stream>>>(
        Af, Bmf, Wtf, RTf, ipb_in, ipb_out, lin_w, lin_b, ob_in, ob_out,
        Bcat, QfT, ycat, bfin);

    mega<<<1024, 256, 0, stream>>>(
        Xbw, Bcat, ycat, QfT, bfin,
        in_idx, out_idx, in_mask, out_mask, (float*)d_out);
}

// Round 8
// 66.453 us; speedup vs baseline: 1.2725x; 1.2725x over previous
//
#include <hip/hip_runtime.h>
#include <math.h>

#define NNODE 32768   // B*N
constexpr float SCALE = 0.08838834764831845f; // 1/sqrt(128)

typedef unsigned short u16;
typedef __bf16 bf16x8 __attribute__((ext_vector_type(8)));
typedef __bf16 bf16x2 __attribute__((ext_vector_type(2)));
typedef float f32x4 __attribute__((ext_vector_type(4)));

__device__ __forceinline__ u16 f2bf(float f) {
    unsigned u = __float_as_uint(f);
    u += 0x7fff + ((u >> 16) & 1);       // RNE
    return (u16)(u >> 16);
}
__device__ __forceinline__ unsigned pack2bf(float lo, float hi) {
    return (unsigned)f2bf(lo) | ((unsigned)f2bf(hi) << 16);
}
__device__ __forceinline__ void unpack8(uint4 u, float* f) {
    f[0] = __uint_as_float(u.x << 16);  f[1] = __uint_as_float(u.x & 0xffff0000u);
    f[2] = __uint_as_float(u.y << 16);  f[3] = __uint_as_float(u.y & 0xffff0000u);
    f[4] = __uint_as_float(u.z << 16);  f[5] = __uint_as_float(u.z & 0xffff0000u);
    f[6] = __uint_as_float(u.w << 16);  f[7] = __uint_as_float(u.w & 0xffff0000u);
}
// packed bf16 pair dot: c += a0*b0 + a1*b1 (v_dot2_f32_bf16 when available)
__device__ __forceinline__ float dot2bf(unsigned a, unsigned b, float c) {
#if __has_builtin(__builtin_amdgcn_fdot2_f32_bf16)
    union { unsigned u; bf16x2 v; } ua, ub;
    ua.u = a; ub.u = b;
    return __builtin_amdgcn_fdot2_f32_bf16(ua.v, ub.v, c, false);
#else
    float al = __uint_as_float(a << 16), ah = __uint_as_float(a & 0xffff0000u);
    float bl = __uint_as_float(b << 16), bh = __uint_as_float(b & 0xffff0000u);
    return fmaf(ah, bh, fmaf(al, bl, c));
#endif
}
__device__ __forceinline__ float dot8bf(uint4 a, uint4 b, float c) {
    c = dot2bf(a.x, b.x, c);
    c = dot2bf(a.y, b.y, c);
    c = dot2bf(a.z, b.z, c);
    c = dot2bf(a.w, b.w, c);
    return c;
}
__device__ __forceinline__ float dot128(const float* __restrict__ a,
                                        const float* __restrict__ b) {
    float s = 0.f;
    #pragma unroll
    for (int c = 0; c < 128; c += 4) {
        float4 x = *(const float4*)&a[c];
        float4 y = *(const float4*)&b[c];
        s = fmaf(x.x, y.x, s); s = fmaf(x.y, y.y, s);
        s = fmaf(x.z, y.z, s); s = fmaf(x.w, y.w, s);
    }
    return s;
}

// async global->LDS, 16B per lane; LDS dest must be wave-uniform base
__device__ __forceinline__ void gl_lds16(const void* g, void* l) {
    __builtin_amdgcn_global_load_lds(
        (const __attribute__((address_space(1))) unsigned int*)(uintptr_t)g,
        (__attribute__((address_space(3))) unsigned int*)(unsigned int)(uintptr_t)l,
        16, 0, 0);
}

// ---------------- weight prep stage 1 ----------------------------------
// Af=Wq@wq^T, Bmf=Wk@wk^T, Wtf=Wv@wv^T ; RT[g][f]=sum_e ow[e][f]*lin_w[g][dir*128+e]
__global__ __launch_bounds__(256) void wprep1(
    const float* __restrict__ ipw_in, const float* __restrict__ ipw_out,
    const float* __restrict__ Wq_in, const float* __restrict__ Wk_in,
    const float* __restrict__ Wv_in,
    const float* __restrict__ Wq_out, const float* __restrict__ Wk_out,
    const float* __restrict__ Wv_out,
    const float* __restrict__ ow_in, const float* __restrict__ ow_out,
    const float* __restrict__ lin_w,
    float* __restrict__ Af, float* __restrict__ Bmf,
    float* __restrict__ Wtf, float* __restrict__ RTf)
{
    int t = blockIdx.x * 256 + threadIdx.x;   // 0..16383
    int i = t >> 7, j = t & 127;
    int task = blockIdx.y, dir = task & 1, kind = task >> 1;
    if (kind < 3) {
        const float* ipw = dir ? ipw_out : ipw_in;
        const float* W; const float* w; float* outp;
        if (kind == 0)      { W = dir ? Wq_out : Wq_in; w = ipw;          outp = Af;  }
        else if (kind == 1) { W = dir ? Wk_out : Wk_in; w = ipw + 16384;  outp = Bmf; }
        else                { W = dir ? Wv_out : Wv_in; w = ipw + 32768;  outp = Wtf; }
        outp[dir * 16384 + i * 128 + j] = dot128(W + i * 128, w + j * 128);
    } else {
        const float* ow = dir ? ow_out : ow_in;
        const float* lw = lin_w + i * 256 + dir * 128;
        float s = 0.f;
        #pragma unroll
        for (int e = 0; e < 128; e += 4) {
            float4 l4 = *(const float4*)&lw[e];
            s = fmaf(ow[e * 128 + j],       l4.x, s);
            s = fmaf(ow[(e + 1) * 128 + j], l4.y, s);
            s = fmaf(ow[(e + 2) * 128 + j], l4.z, s);
            s = fmaf(ow[(e + 3) * 128 + j], l4.w, s);
        }
        RTf[dir * 16384 + i * 128 + j] = s;
    }
}

// ---------------- weight prep stage 2 ----------------------------------
// Bcat[dir*128+d][c] = SCALE * sum_f A[c][f]*Bm[d][f]   (bf16, pre-scaled)
// QfT[g][dir*128+c]  = sum_f Wt[c][f]*RT[g][f]          (bf16)
// ycat[dir*128+d] = SCALE * (Bm_row_d . bq)
// bfin[g] = lin_b[g] + sum_dir(bv.RT_g + ob.lw_g)
__global__ __launch_bounds__(256) void wprep2(
    const float* __restrict__ Af, const float* __restrict__ Bmf,
    const float* __restrict__ Wtf, const float* __restrict__ RTf,
    const float* __restrict__ ipb_in, const float* __restrict__ ipb_out,
    const float* __restrict__ lin_w, const float* __restrict__ lin_b,
    const float* __restrict__ ob_in, const float* __restrict__ ob_out,
    u16* __restrict__ Bcat, u16* __restrict__ QfT,
    float* __restrict__ ycat, float* __restrict__ bfin)
{
    int task = blockIdx.y;
    int t = blockIdx.x * 256 + threadIdx.x;
    if (task < 2) {
        int dir = task, i = t >> 7, j = t & 127;          // i=d, j=c
        float s = dot128(Af + dir * 16384 + j * 128, Bmf + dir * 16384 + i * 128);
        Bcat[(size_t)(dir * 128 + i) * 128 + j] = f2bf(s * SCALE);
    } else if (task < 4) {
        int dir = task - 2, i = t >> 7, j = t & 127;      // i=g, j=c
        float s = dot128(Wtf + dir * 16384 + j * 128, RTf + dir * 16384 + i * 128);
        QfT[(size_t)i * 256 + dir * 128 + j] = f2bf(s);
    } else {
        if (t < 256) {
            int dir = t >> 7, d = t & 127;
            const float* bq = dir ? ipb_out : ipb_in;
            const float* rb = Bmf + dir * 16384 + d * 128;
            float s = 0.f;
            for (int f = 0; f < 128; ++f) s = fmaf(rb[f], bq[f], s);
            ycat[t] = s * SCALE;
        } else if (t < 384) {
            int g = t - 256;
            float s = lin_b[g];
            #pragma unroll
            for (int dir = 0; dir < 2; ++dir) {
                const float* bv = (dir ? ipb_out : ipb_in) + 256;
                const float* rt = RTf + dir * 16384 + g * 128;
                const float* ob = dir ? ob_out : ob_in;
                const float* lw = lin_w + g * 256 + dir * 128;
                for (int c = 0; c < 128; ++c)
                    s += bv[c] * rt[c] + ob[c] * lw[c];
            }
            bfin[g] = s;
        }
    }
}

// ---------------- kernel: Y GEMM (also emits Xb) -----------------------
// Y[32768][256] = bf16(X) @ Bcat^T + ycat ; Xb = bf16(X) written en route
template<int NT>
__global__ __launch_bounds__(256) void gemm_y(
    const float* __restrict__ X,
    const u16* __restrict__ BT,
    const float* __restrict__ bias,
    u16* __restrict__ C, u16* __restrict__ Xb)
{
    __shared__ __align__(16) u16 As[128 * 128];
    __shared__ __align__(16) u16 Bs[128 * 128];
    const int tid  = threadIdx.x;
    const int lane = tid & 63;
    const int wid  = tid >> 6;
    const int bm  = blockIdx.x * 128;
    const int wr = wid >> 1, wc = wid & 1;
    const int l15 = lane & 15, l4 = lane >> 4;

    // stage A: read f32 X, convert, swizzled ds_write; also write Xb global
    #pragma unroll
    for (int i = 0; i < 8; ++i) {
        int c = i * 256 + tid;          // chunk id 0..2047
        int r = c >> 4, cb = c & 15;
        const float* src = &X[(size_t)(bm + r) * 128 + cb * 8];
        float4 f0 = *(const float4*)src;
        float4 f1 = *(const float4*)(src + 4);
        uint4 pk;
        pk.x = pack2bf(f0.x, f0.y); pk.y = pack2bf(f0.z, f0.w);
        pk.z = pack2bf(f1.x, f1.y); pk.w = pack2bf(f1.z, f1.w);
        *(uint4*)&As[r * 128 + ((cb ^ (r & 7)) * 8)] = pk;
        *(uint4*)&Xb[(size_t)(bm + r) * 128 + cb * 8] = pk;
    }
    __syncthreads();
    bf16x8 a[4][4];
    #pragma unroll
    for (int ks = 0; ks < 4; ++ks)
        #pragma unroll
        for (int mr = 0; mr < 4; ++mr) {
            int r = wr * 64 + mr * 16 + l15;
            int kb = ks * 4 + l4;
            a[ks][mr] = *(const bf16x8*)((const char*)As + r * 256 + ((kb ^ (r & 7)) << 4));
        }

    #pragma unroll
    for (int nt = 0; nt < NT; ++nt) {
        int bn = nt * 128;
        __syncthreads();
        #pragma unroll
        for (int i = 0; i < 8; ++i) {
            int c = i * 256 + tid;
            int r = c >> 4, cb = c & 15;
            gl_lds16(&BT[(size_t)(bn + r) * 128 + 8 * (cb ^ (r & 7))],
                     &Bs[(size_t)(c - lane) * 8]);
        }
        __syncthreads();

        f32x4 acc[4][4] = {};
        #pragma unroll
        for (int ks = 0; ks < 4; ++ks) {
            bf16x8 bfr[4];
            #pragma unroll
            for (int nc = 0; nc < 4; ++nc) {
                int r = wc * 64 + nc * 16 + l15;
                int kb = ks * 4 + l4;
                bfr[nc] = *(const bf16x8*)((const char*)Bs + r * 256 + ((kb ^ (r & 7)) << 4));
            }
            #pragma unroll
            for (int mr = 0; mr < 4; ++mr)
                #pragma unroll
                for (int nc = 0; nc < 4; ++nc)
                    acc[mr][nc] = __builtin_amdgcn_mfma_f32_16x16x32_bf16(
                        a[ks][mr], bfr[nc], acc[mr][nc], 0, 0, 0);
        }
        #pragma unroll
        for (int nc = 0; nc < 4; ++nc) {
            int col = bn + wc * 64 + nc * 16 + l15;
            float bv = bias[col];
            #pragma unroll
            for (int mr = 0; mr < 4; ++mr)
                #pragma unroll
                for (int j = 0; j < 4; ++j) {
                    int row = bm + wr * 64 + mr * 16 + l4 * 4 + j;
                    C[(size_t)row * 256 + col] = f2bf(acc[mr][nc][j] + bv);
                }
        }
    }
}

// ---------------- output GEMM + ELU (K=256) ----------------------------
template<int KTOT, bool ELU_F32>
__global__ __launch_bounds__(256) void gemm_mfma(
    const u16* __restrict__ A,
    const u16* __restrict__ BT,
    const float* __restrict__ bias,
    void* __restrict__ Cout, int ldc)
{
    __shared__ __align__(16) u16 As[128 * 128];
    __shared__ __align__(16) u16 Bs[128 * 128];
    const int tid  = threadIdx.x;
    const int lane = tid & 63;
    const int wid  = tid >> 6;
    const int bm = blockIdx.x * 128;
    const int bn = blockIdx.y * 128;
    const int wr = wid >> 1, wc = wid & 1;
    const int l15 = lane & 15, l4 = lane >> 4;

    f32x4 acc[4][4] = {};

    for (int k0 = 0; k0 < KTOT; k0 += 128) {
        #pragma unroll
        for (int i = 0; i < 8; ++i) {
            int c = i * 256 + tid;
            int r = c >> 4, cb = c & 15;
            int col = k0 + 8 * (cb ^ (r & 7));
            gl_lds16(&A[(size_t)(bm + r) * KTOT + col], &As[(size_t)(c - lane) * 8]);
            gl_lds16(&BT[(size_t)(bn + r) * KTOT + col], &Bs[(size_t)(c - lane) * 8]);
        }
        __syncthreads();
        #pragma unroll
        for (int ks = 0; ks < 4; ++ks) {
            bf16x8 a[4], b[4];
            #pragma unroll
            for (int mr = 0; mr < 4; ++mr) {
                int r = wr * 64 + mr * 16 + l15;
                int kb = ks * 4 + l4;
                a[mr] = *(const bf16x8*)((const char*)As + r * 256 + ((kb ^ (r & 7)) << 4));
            }
            #pragma unroll
            for (int nc = 0; nc < 4; ++nc) {
                int r = wc * 64 + nc * 16 + l15;
                int kb = ks * 4 + l4;
                b[nc] = *(const bf16x8*)((const char*)Bs + r * 256 + ((kb ^ (r & 7)) << 4));
            }
            #pragma unroll
            for (int mr = 0; mr < 4; ++mr)
                #pragma unroll
                for (int nc = 0; nc < 4; ++nc)
                    acc[mr][nc] = __builtin_amdgcn_mfma_f32_16x16x32_bf16(
                        a[mr], b[nc], acc[mr][nc], 0, 0, 0);
        }
        __syncthreads();
    }

    #pragma unroll
    for (int nc = 0; nc < 4; ++nc) {
        int col = bn + wc * 64 + nc * 16 + l15;
        float bv = bias[col];
        #pragma unroll
        for (int mr = 0; mr < 4; ++mr) {
            #pragma unroll
            for (int j = 0; j < 4; ++j) {
                int row = bm + wr * 64 + mr * 16 + l4 * 4 + j;
                float v = acc[mr][nc][j] + bv;
                if (ELU_F32) {
                    v = v > 0.f ? v : (__expf(v) - 1.f);
                    ((float*)Cout)[(size_t)row * ldc + col] = v;
                } else {
                    ((u16*)Cout)[(size_t)row * ldc + col] = f2bf(v);
                }
            }
        }
    }
}

// ---------------- attention: Y.X scores (dot2), XCTX = sum w*X ---------
// 16 lanes per (node,dir); gathers only Xb rows (shared across dirs).
// Scores pre-scaled (SCALE folded into Bcat/ycat). K-pass uses packed
// v_dot2_f32_bf16 (no unpack); V-pass unpacks once.
__global__ __launch_bounds__(256) void attn_kernel(
    const u16* __restrict__ Y, const u16* __restrict__ Xb,
    const int* __restrict__ in_idx, const int* __restrict__ out_idx,
    const int* __restrict__ in_mask, const int* __restrict__ out_mask,
    u16* __restrict__ XCTX)
{
    const int tid = threadIdx.x;
    const int g   = tid >> 4;        // item 0..15 within block
    const int l   = tid & 15;        // lane within group
    const int pair = blockIdx.x & 7;
    const int dir = pair & 1, b = pair >> 1;
    const int nl = ((blockIdx.x >> 3) << 4) + g;       // 0..8191
    const int node = (b << 13) + nl;
    const int* idx = dir == 0 ? in_idx : out_idx;
    const int* msk = dir == 0 ? in_mask : out_mask;

    const int4 i0 = *(const int4*)&idx[(size_t)node * 8];
    const int4 i1 = *(const int4*)&idx[(size_t)node * 8 + 4];
    const int4 m0 = *(const int4*)&msk[(size_t)node * 8];
    const int4 m1 = *(const int4*)&msk[(size_t)node * 8 + 4];
    const int ii[8] = { i0.x, i0.y, i0.z, i0.w, i1.x, i1.y, i1.z, i1.w };
    const int mm[8] = { m0.x, m0.y, m0.z, m0.w, m1.x, m1.y, m1.z, m1.w };

    // issue all loads up front: Y row (self) + 9 Xb rows
    uint4 yv = *(const uint4*)&Y[(size_t)node * 256 + dir * 128 + l * 8];
    uint4 xv[9];
    xv[0] = *(const uint4*)&Xb[(size_t)node * 128 + l * 8];
    #pragma unroll
    for (int s = 0; s < 8; ++s)
        xv[s + 1] = *(const uint4*)&Xb[(size_t)((b << 13) + ii[s]) * 128 + l * 8];

    // K-pass: packed dot2, no unpack
    float sc[9];
    #pragma unroll
    for (int s = 0; s < 9; ++s)
        sc[s] = dot8bf(yv, xv[s], 0.f);

    // 4-step butterfly within each 16-lane group; 9 independent chains
    #pragma unroll
    for (int s = 0; s < 9; ++s) {
        float x = sc[s];
        x += __shfl_xor(x, 1);
        x += __shfl_xor(x, 2);
        x += __shfl_xor(x, 4);
        x += __shfl_xor(x, 8);
        sc[s] = x;                       // already scaled via Bcat/ycat
    }
    #pragma unroll
    for (int s = 1; s < 9; ++s)
        sc[s] = mm[s - 1] ? sc[s] : -1e30f;

    float m = sc[0];
    #pragma unroll
    for (int s = 1; s < 9; ++s) m = fmaxf(m, sc[s]);
    float w[9], wsum = 0.f;
    #pragma unroll
    for (int s = 0; s < 9; ++s) { w[s] = __expf(sc[s] - m); wsum += w[s]; }
    const float inv = 1.f / wsum;

    // V-pass: weighted sum of the SAME gathered rows (w==0 for invalid)
    float acc[8] = {};
    #pragma unroll
    for (int s = 0; s < 9; ++s) {
        float vf[8];
        unpack8(xv[s], vf);
        #pragma unroll
        for (int j = 0; j < 8; ++j) acc[j] = fmaf(w[s], vf[j], acc[j]);
    }
    uint4 o;
    o.x = pack2bf(acc[0] * inv, acc[1] * inv);
    o.y = pack2bf(acc[2] * inv, acc[3] * inv);
    o.z = pack2bf(acc[4] * inv, acc[5] * inv);
    o.w = pack2bf(acc[6] * inv, acc[7] * inv);
    *(uint4*)&XCTX[(size_t)node * 256 + dir * 128 + l * 8] = o;
}

// ---------------- launch ----------------------------------------------
extern "C" void kernel_launch(void* const* d_in, const int* in_sizes, int n_in,
                              void* d_out, int out_size, void* d_ws, size_t ws_size,
                              hipStream_t stream) {
    const float* X        = (const float*)d_in[0];
    const int*   in_idx   = (const int*)d_in[1];
    const int*   out_idx  = (const int*)d_in[2];
    const int*   in_mask  = (const int*)d_in[3];
    const int*   out_mask = (const int*)d_in[4];
    const float* Wq_in  = (const float*)d_in[5];
    const float* Wk_in  = (const float*)d_in[6];
    const float* Wv_in  = (const float*)d_in[7];
    const float* ipw_in = (const float*)d_in[8];
    const float* ipb_in = (const float*)d_in[9];
    const float* ow_in  = (const float*)d_in[10];
    const float* ob_in  = (const float*)d_in[11];
    const float* Wq_out  = (const float*)d_in[12];
    const float* Wk_out  = (const float*)d_in[13];
    const float* Wv_out  = (const float*)d_in[14];
    const float* ipw_out = (const float*)d_in[15];
    const float* ipb_out = (const float*)d_in[16];
    const float* ow_out  = (const float*)d_in[17];
    const float* ob_out  = (const float*)d_in[18];
    const float* lin_w   = (const float*)d_in[19];
    const float* lin_b   = (const float*)d_in[20];

    char* wsb = (char*)d_ws;
    u16*   Xbw  = (u16*)(wsb + 0);                    //  8,388,608 B
    u16*   Yw   = (u16*)(wsb + 8388608);              // 16,777,216 B
    u16*   XCTX = (u16*)(wsb + 25165824);             // 16,777,216 B
    u16*   Bcat = (u16*)(wsb + 41943040);             //     65,536 B
    u16*   QfT  = (u16*)(wsb + 42008576);             //     65,536 B
    float* Af   = (float*)(wsb + 42074112);           //    131,072 B
    float* Bmf  = (float*)(wsb + 42205184);
    float* Wtf  = (float*)(wsb + 42336256);
    float* RTf  = (float*)(wsb + 42467328);
    float* ycat = (float*)(wsb + 42598400);           //      1,024 B
    float* bfin = (float*)(wsb + 42599424);           //        512 B

    wprep1<<<dim3(64, 8), 256, 0, stream>>>(
        ipw_in, ipw_out, Wq_in, Wk_in, Wv_in, Wq_out, Wk_out, Wv_out,
        ow_in, ow_out, lin_w, Af, Bmf, Wtf, RTf);

    wprep2<<<dim3(64, 5), 256, 0, stream>>>(
        Af, Bmf, Wtf, RTf, ipb_in, ipb_out, lin_w, lin_b, ob_in, ob_out,
        Bcat, QfT, ycat, bfin);

    gemm_y<2><<<dim3(256, 1), 256, 0, stream>>>(X, Bcat, ycat, Yw, Xbw);

    attn_kernel<<<4096, 256, 0, stream>>>(
        Yw, Xbw, in_idx, out_idx, in_mask, out_mask, XCTX);

    gemm_mfma<256, true><<<dim3(256, 1), 256, 0, stream>>>(
        XCTX, QfT, bfin, (float*)d_out, 128);
}

// Round 9
// 65.218 us; speedup vs baseline: 1.2966x; 1.0189x over previous
//
#include <hip/hip_runtime.h>
#include <math.h>

#define NNODE 32768   // B*N
constexpr float SCALE = 0.08838834764831845f; // 1/sqrt(128)

typedef unsigned short u16;
typedef __bf16 bf16x8 __attribute__((ext_vector_type(8)));
typedef __bf16 bf16x2 __attribute__((ext_vector_type(2)));
typedef float f32x4 __attribute__((ext_vector_type(4)));

__device__ __forceinline__ u16 f2bf(float f) {
    unsigned u = __float_as_uint(f);
    u += 0x7fff + ((u >> 16) & 1);       // RNE
    return (u16)(u >> 16);
}
__device__ __forceinline__ unsigned pack2bf(float lo, float hi) {
    return (unsigned)f2bf(lo) | ((unsigned)f2bf(hi) << 16);
}
__device__ __forceinline__ void unpack8(uint4 u, float* f) {
    f[0] = __uint_as_float(u.x << 16);  f[1] = __uint_as_float(u.x & 0xffff0000u);
    f[2] = __uint_as_float(u.y << 16);  f[3] = __uint_as_float(u.y & 0xffff0000u);
    f[4] = __uint_as_float(u.z << 16);  f[5] = __uint_as_float(u.z & 0xffff0000u);
    f[6] = __uint_as_float(u.w << 16);  f[7] = __uint_as_float(u.w & 0xffff0000u);
}
// packed bf16 pair dot: c += a0*b0 + a1*b1 (v_dot2_f32_bf16 when available)
__device__ __forceinline__ float dot2bf(unsigned a, unsigned b, float c) {
#if __has_builtin(__builtin_amdgcn_fdot2_f32_bf16)
    union { unsigned u; bf16x2 v; } ua, ub;
    ua.u = a; ub.u = b;
    return __builtin_amdgcn_fdot2_f32_bf16(ua.v, ub.v, c, false);
#else
    float al = __uint_as_float(a << 16), ah = __uint_as_float(a & 0xffff0000u);
    float bl = __uint_as_float(b << 16), bh = __uint_as_float(b & 0xffff0000u);
    return fmaf(ah, bh, fmaf(al, bl, c));
#endif
}
__device__ __forceinline__ float dot8bf(uint4 a, uint4 b, float c) {
    c = dot2bf(a.x, b.x, c);
    c = dot2bf(a.y, b.y, c);
    c = dot2bf(a.z, b.z, c);
    c = dot2bf(a.w, b.w, c);
    return c;
}
__device__ __forceinline__ float dot128(const float* __restrict__ a,
                                        const float* __restrict__ b) {
    float s = 0.f;
    #pragma unroll
    for (int c = 0; c < 128; c += 4) {
        float4 x = *(const float4*)&a[c];
        float4 y = *(const float4*)&b[c];
        s = fmaf(x.x, y.x, s); s = fmaf(x.y, y.y, s);
        s = fmaf(x.z, y.z, s); s = fmaf(x.w, y.w, s);
    }
    return s;
}

// async global->LDS, 16B per lane; LDS dest must be wave-uniform base
__device__ __forceinline__ void gl_lds16(const void* g, void* l) {
    __builtin_amdgcn_global_load_lds(
        (const __attribute__((address_space(1))) unsigned int*)(uintptr_t)g,
        (__attribute__((address_space(3))) unsigned int*)(unsigned int)(uintptr_t)l,
        16, 0, 0);
}

// ---------------- weight prep stage 1 ----------------------------------
// Af=Wq@wq^T, Bmf=Wk@wk^T, Wtf=Wv@wv^T ; RT[g][f]=sum_e ow[e][f]*lin_w[g][dir*128+e]
__global__ __launch_bounds__(256) void wprep1(
    const float* __restrict__ ipw_in, const float* __restrict__ ipw_out,
    const float* __restrict__ Wq_in, const float* __restrict__ Wk_in,
    const float* __restrict__ Wv_in,
    const float* __restrict__ Wq_out, const float* __restrict__ Wk_out,
    const float* __restrict__ Wv_out,
    const float* __restrict__ ow_in, const float* __restrict__ ow_out,
    const float* __restrict__ lin_w,
    float* __restrict__ Af, float* __restrict__ Bmf,
    float* __restrict__ Wtf, float* __restrict__ RTf)
{
    int t = blockIdx.x * 256 + threadIdx.x;   // 0..16383
    int i = t >> 7, j = t & 127;
    int task = blockIdx.y, dir = task & 1, kind = task >> 1;
    if (kind < 3) {
        const float* ipw = dir ? ipw_out : ipw_in;
        const float* W; const float* w; float* outp;
        if (kind == 0)      { W = dir ? Wq_out : Wq_in; w = ipw;          outp = Af;  }
        else if (kind == 1) { W = dir ? Wk_out : Wk_in; w = ipw + 16384;  outp = Bmf; }
        else                { W = dir ? Wv_out : Wv_in; w = ipw + 32768;  outp = Wtf; }
        outp[dir * 16384 + i * 128 + j] = dot128(W + i * 128, w + j * 128);
    } else {
        const float* ow = dir ? ow_out : ow_in;
        const float* lw = lin_w + i * 256 + dir * 128;
        float s = 0.f;
        #pragma unroll
        for (int e = 0; e < 128; e += 4) {
            float4 l4 = *(const float4*)&lw[e];
            s = fmaf(ow[e * 128 + j],       l4.x, s);
            s = fmaf(ow[(e + 1) * 128 + j], l4.y, s);
            s = fmaf(ow[(e + 2) * 128 + j], l4.z, s);
            s = fmaf(ow[(e + 3) * 128 + j], l4.w, s);
        }
        RTf[dir * 16384 + i * 128 + j] = s;
    }
}

// ---------------- weight prep stage 2 ----------------------------------
// Bcat[dir*128+d][c] = SCALE * sum_f A[c][f]*Bm[d][f]   (bf16, pre-scaled)
// QfT[g][dir*128+c]  = sum_f Wt[c][f]*RT[g][f]          (bf16)
// ycat[dir*128+d] = SCALE * (Bm_row_d . bq)
// bfin[g] = lin_b[g] + sum_dir(bv.RT_g + ob.lw_g)
__global__ __launch_bounds__(256) void wprep2(
    const float* __restrict__ Af, const float* __restrict__ Bmf,
    const float* __restrict__ Wtf, const float* __restrict__ RTf,
    const float* __restrict__ ipb_in, const float* __restrict__ ipb_out,
    const float* __restrict__ lin_w, const float* __restrict__ lin_b,
    const float* __restrict__ ob_in, const float* __restrict__ ob_out,
    u16* __restrict__ Bcat, u16* __restrict__ QfT,
    float* __restrict__ ycat, float* __restrict__ bfin)
{
    int task = blockIdx.y;
    int t = blockIdx.x * 256 + threadIdx.x;
    if (task < 2) {
        int dir = task, i = t >> 7, j = t & 127;          // i=d, j=c
        float s = dot128(Af + dir * 16384 + j * 128, Bmf + dir * 16384 + i * 128);
        Bcat[(size_t)(dir * 128 + i) * 128 + j] = f2bf(s * SCALE);
    } else if (task < 4) {
        int dir = task - 2, i = t >> 7, j = t & 127;      // i=g, j=c
        float s = dot128(Wtf + dir * 16384 + j * 128, RTf + dir * 16384 + i * 128);
        QfT[(size_t)i * 256 + dir * 128 + j] = f2bf(s);
    } else {
        if (t < 256) {
            int dir = t >> 7, d = t & 127;
            const float* bq = dir ? ipb_out : ipb_in;
            const float* rb = Bmf + dir * 16384 + d * 128;
            float s = 0.f;
            for (int f = 0; f < 128; ++f) s = fmaf(rb[f], bq[f], s);
            ycat[t] = s * SCALE;
        } else if (t < 384) {
            int g = t - 256;
            float s = lin_b[g];
            #pragma unroll
            for (int dir = 0; dir < 2; ++dir) {
                const float* bv = (dir ? ipb_out : ipb_in) + 256;
                const float* rt = RTf + dir * 16384 + g * 128;
                const float* ob = dir ? ob_out : ob_in;
                const float* lw = lin_w + g * 256 + dir * 128;
                for (int c = 0; c < 128; ++c)
                    s += bv[c] * rt[c] + ob[c] * lw[c];
            }
            bfin[g] = s;
        }
    }
}

// ---------------- kernel: Y GEMM (also emits Xb) -----------------------
// Y[32768][256] = bf16(X) @ Bcat^T + ycat ; Xb = bf16(X) written en route
template<int NT>
__global__ __launch_bounds__(256) void gemm_y(
    const float* __restrict__ X,
    const u16* __restrict__ BT,
    const float* __restrict__ bias,
    u16* __restrict__ C, u16* __restrict__ Xb)
{
    __shared__ __align__(16) u16 As[128 * 128];
    __shared__ __align__(16) u16 Bs[128 * 128];
    const int tid  = threadIdx.x;
    const int lane = tid & 63;
    const int wid  = tid >> 6;
    const int bm  = blockIdx.x * 128;
    const int wr = wid >> 1, wc = wid & 1;
    const int l15 = lane & 15, l4 = lane >> 4;

    // stage A: read f32 X, convert, swizzled ds_write; also write Xb global
    #pragma unroll
    for (int i = 0; i < 8; ++i) {
        int c = i * 256 + tid;          // chunk id 0..2047
        int r = c >> 4, cb = c & 15;
        const float* src = &X[(size_t)(bm + r) * 128 + cb * 8];
        float4 f0 = *(const float4*)src;
        float4 f1 = *(const float4*)(src + 4);
        uint4 pk;
        pk.x = pack2bf(f0.x, f0.y); pk.y = pack2bf(f0.z, f0.w);
        pk.z = pack2bf(f1.x, f1.y); pk.w = pack2bf(f1.z, f1.w);
        *(uint4*)&As[r * 128 + ((cb ^ (r & 7)) * 8)] = pk;
        *(uint4*)&Xb[(size_t)(bm + r) * 128 + cb * 8] = pk;
    }
    __syncthreads();
    bf16x8 a[4][4];
    #pragma unroll
    for (int ks = 0; ks < 4; ++ks)
        #pragma unroll
        for (int mr = 0; mr < 4; ++mr) {
            int r = wr * 64 + mr * 16 + l15;
            int kb = ks * 4 + l4;
            a[ks][mr] = *(const bf16x8*)((const char*)As + r * 256 + ((kb ^ (r & 7)) << 4));
        }

    #pragma unroll
    for (int nt = 0; nt < NT; ++nt) {
        int bn = nt * 128;
        __syncthreads();
        #pragma unroll
        for (int i = 0; i < 8; ++i) {
            int c = i * 256 + tid;
            int r = c >> 4, cb = c & 15;
            gl_lds16(&BT[(size_t)(bn + r) * 128 + 8 * (cb ^ (r & 7))],
                     &Bs[(size_t)(c - lane) * 8]);
        }
        __syncthreads();

        f32x4 acc[4][4] = {};
        #pragma unroll
        for (int ks = 0; ks < 4; ++ks) {
            bf16x8 bfr[4];
            #pragma unroll
            for (int nc = 0; nc < 4; ++nc) {
                int r = wc * 64 + nc * 16 + l15;
                int kb = ks * 4 + l4;
                bfr[nc] = *(const bf16x8*)((const char*)Bs + r * 256 + ((kb ^ (r & 7)) << 4));
            }
            #pragma unroll
            for (int mr = 0; mr < 4; ++mr)
                #pragma unroll
                for (int nc = 0; nc < 4; ++nc)
                    acc[mr][nc] = __builtin_amdgcn_mfma_f32_16x16x32_bf16(
                        a[ks][mr], bfr[nc], acc[mr][nc], 0, 0, 0);
        }
        #pragma unroll
        for (int nc = 0; nc < 4; ++nc) {
            int col = bn + wc * 64 + nc * 16 + l15;
            float bv = bias[col];
            #pragma unroll
            for (int mr = 0; mr < 4; ++mr)
                #pragma unroll
                for (int j = 0; j < 4; ++j) {
                    int row = bm + wr * 64 + mr * 16 + l4 * 4 + j;
                    C[(size_t)row * 256 + col] = f2bf(acc[mr][nc][j] + bv);
                }
        }
    }
}

// ---------------- fused attention + output GEMM ------------------------
// Per block: 32 nodes, both dirs. P2: 64 attn items in 4 rounds, results
// to swizzled LDS XC[32][256]. P3: out[32][128] = elu(XC @ QfT^T + bfin).
// bid&7 keys (batch, parity) -> each XCD's gathers stay in one batch's
// 2MB Xb pool (L2-resident).
__global__ __launch_bounds__(256) void attn_out(
    const u16* __restrict__ Y, const u16* __restrict__ Xb,
    const int* __restrict__ in_idx, const int* __restrict__ out_idx,
    const int* __restrict__ in_mask, const int* __restrict__ out_mask,
    const u16* __restrict__ QfT, const float* __restrict__ bfin,
    float* __restrict__ Cout)
{
    __shared__ __align__(16) u16 XC[32 * 256];   // 16 KB, XOR-swizzled

    const int tid  = threadIdx.x;
    const int lane = tid & 63;
    const int wid  = tid >> 6;
    const int l15  = lane & 15, l4 = lane >> 4;

    const int bid  = blockIdx.x;
    const int b    = (bid & 7) >> 1;
    const int s    = ((bid >> 3) << 1) + (bid & 1);   // 0..255
    const int node0 = (b << 13) + s * 32;

    // ---- P2: attention, 64 items (node r, dir) in 4 rounds of 16 groups
    {
        const int g = tid >> 4, l = tid & 15;
        #pragma unroll
        for (int round = 0; round < 4; ++round) {
            const int item = round * 16 + g;
            const int r   = item & 31;
            const int dir = item >> 5;
            const int node = node0 + r;
            const int* idx = dir ? out_idx : in_idx;
            const int* msk = dir ? out_mask : in_mask;

            const int4 i0 = *(const int4*)&idx[(size_t)node * 8];
            const int4 i1 = *(const int4*)&idx[(size_t)node * 8 + 4];
            const int4 m0 = *(const int4*)&msk[(size_t)node * 8];
            const int4 m1 = *(const int4*)&msk[(size_t)node * 8 + 4];
            const int ii[8] = { i0.x, i0.y, i0.z, i0.w, i1.x, i1.y, i1.z, i1.w };
            const int mm[8] = { m0.x, m0.y, m0.z, m0.w, m1.x, m1.y, m1.z, m1.w };

            // issue all loads up front: Y row (self) + 9 Xb rows
            uint4 yv = *(const uint4*)&Y[(size_t)node * 256 + dir * 128 + l * 8];
            uint4 xv[9];
            xv[0] = *(const uint4*)&Xb[(size_t)node * 128 + l * 8];
            #pragma unroll
            for (int t2 = 0; t2 < 8; ++t2)
                xv[t2 + 1] = *(const uint4*)&Xb[(size_t)((b << 13) + ii[t2]) * 128 + l * 8];

            // K-pass: packed dot2, scores pre-scaled via Bcat/ycat
            float sc[9];
            #pragma unroll
            for (int t2 = 0; t2 < 9; ++t2)
                sc[t2] = dot8bf(yv, xv[t2], 0.f);

            #pragma unroll
            for (int t2 = 0; t2 < 9; ++t2) {
                float x = sc[t2];
                x += __shfl_xor(x, 1);
                x += __shfl_xor(x, 2);
                x += __shfl_xor(x, 4);
                x += __shfl_xor(x, 8);
                sc[t2] = x;
            }
            #pragma unroll
            for (int t2 = 1; t2 < 9; ++t2)
                sc[t2] = mm[t2 - 1] ? sc[t2] : -1e30f;

            float m = sc[0];
            #pragma unroll
            for (int t2 = 1; t2 < 9; ++t2) m = fmaxf(m, sc[t2]);
            float w[9], wsum = 0.f;
            #pragma unroll
            for (int t2 = 0; t2 < 9; ++t2) { w[t2] = __expf(sc[t2] - m); wsum += w[t2]; }
            const float inv = 1.f / wsum;

            float acc[8] = {};
            #pragma unroll
            for (int t2 = 0; t2 < 9; ++t2) {
                float vf[8];
                unpack8(xv[t2], vf);
                #pragma unroll
                for (int j = 0; j < 8; ++j) acc[j] = fmaf(w[t2], vf[j], acc[j]);
            }
            uint4 o;
            o.x = pack2bf(acc[0] * inv, acc[1] * inv);
            o.y = pack2bf(acc[2] * inv, acc[3] * inv);
            o.z = pack2bf(acc[4] * inv, acc[5] * inv);
            o.w = pack2bf(acc[6] * inv, acc[7] * inv);
            const int chunk = (dir << 4) + l;            // 0..31
            *(uint4*)((char*)XC + r * 512 + ((chunk ^ (r & 7)) << 4)) = o;
        }
    }
    __syncthreads();

    // ---- P3: out = elu(XC @ QfT^T + bfin) -> f32 ----
    {
        f32x4 acc[2][2] = {};
        #pragma unroll
        for (int ks = 0; ks < 8; ++ks) {
            bf16x8 a[2], bb[2];
            #pragma unroll
            for (int mr = 0; mr < 2; ++mr) {
                int r = mr * 16 + l15;
                int kb = ks * 4 + l4;
                a[mr] = *(const bf16x8*)((const char*)XC + r * 512 + ((kb ^ (r & 7)) << 4));
            }
            #pragma unroll
            for (int nc = 0; nc < 2; ++nc) {
                int col = wid * 32 + nc * 16 + l15;
                bb[nc] = *(const bf16x8*)&QfT[(size_t)col * 256 + (ks * 4 + l4) * 8];
            }
            #pragma unroll
            for (int mr = 0; mr < 2; ++mr)
                #pragma unroll
                for (int nc = 0; nc < 2; ++nc)
                    acc[mr][nc] = __builtin_amdgcn_mfma_f32_16x16x32_bf16(
                        a[mr], bb[nc], acc[mr][nc], 0, 0, 0);
        }
        #pragma unroll
        for (int nc = 0; nc < 2; ++nc) {
            int col = wid * 32 + nc * 16 + l15;
            float bv = bfin[col];
            #pragma unroll
            for (int mr = 0; mr < 2; ++mr)
                #pragma unroll
                for (int j = 0; j < 4; ++j) {
                    int row = mr * 16 + l4 * 4 + j;
                    float v = acc[mr][nc][j] + bv;
                    v = v > 0.f ? v : (__expf(v) - 1.f);
                    Cout[(size_t)(node0 + row) * 128 + col] = v;
                }
        }
    }
}

// ---------------- launch ----------------------------------------------
extern "C" void kernel_launch(void* const* d_in, const int* in_sizes, int n_in,
                              void* d_out, int out_size, void* d_ws, size_t ws_size,
                              hipStream_t stream) {
    const float* X        = (const float*)d_in[0];
    const int*   in_idx   = (const int*)d_in[1];
    const int*   out_idx  = (const int*)d_in[2];
    const int*   in_mask  = (const int*)d_in[3];
    const int*   out_mask = (const int*)d_in[4];
    const float* Wq_in  = (const float*)d_in[5];
    const float* Wk_in  = (const float*)d_in[6];
    const float* Wv_in  = (const float*)d_in[7];
    const float* ipw_in = (const float*)d_in[8];
    const float* ipb_in = (const float*)d_in[9];
    const float* ow_in  = (const float*)d_in[10];
    const float* ob_in  = (const float*)d_in[11];
    const float* Wq_out  = (const float*)d_in[12];
    const float* Wk_out  = (const float*)d_in[13];
    const float* Wv_out  = (const float*)d_in[14];
    const float* ipw_out = (const float*)d_in[15];
    const float* ipb_out = (const float*)d_in[16];
    const float* ow_out  = (const float*)d_in[17];
    const float* ob_out  = (const float*)d_in[18];
    const float* lin_w   = (const float*)d_in[19];
    const float* lin_b   = (const float*)d_in[20];

    char* wsb = (char*)d_ws;
    u16*   Xbw  = (u16*)(wsb + 0);                    //  8,388,608 B
    u16*   Yw   = (u16*)(wsb + 8388608);              // 16,777,216 B
    u16*   Bcat = (u16*)(wsb + 25165824);             //     65,536 B
    u16*   QfT  = (u16*)(wsb + 25231360);             //     65,536 B
    float* Af   = (float*)(wsb + 25296896);           //    131,072 B
    float* Bmf  = (float*)(wsb + 25427968);
    float* Wtf  = (float*)(wsb + 25559040);
    float* RTf  = (float*)(wsb + 25690112);
    float* ycat = (float*)(wsb + 25821184);           //      1,024 B
    float* bfin = (float*)(wsb + 25822208);           //        512 B

    wprep1<<<dim3(64, 8), 256, 0, stream>>>(
        ipw_in, ipw_out, Wq_in, Wk_in, Wv_in, Wq_out, Wk_out, Wv_out,
        ow_in, ow_out, lin_w, Af, Bmf, Wtf, RTf);

    wprep2<<<dim3(64, 5), 256, 0, stream>>>(
        Af, Bmf, Wtf, RTf, ipb_in, ipb_out, lin_w, lin_b, ob_in, ob_out,
        Bcat, QfT, ycat, bfin);

    gemm_y<2><<<dim3(256, 1), 256, 0, stream>>>(X, Bcat, ycat, Yw, Xbw);

    attn_out<<<1024, 256, 0, stream>>>(
        Yw, Xbw, in_idx, out_idx, in_mask, out_mask,
        QfT, bfin, (float*)d_out);
}